// Round 12
// baseline (142.825 us; speedup 1.0000x reference)
//
#include <hip/hip_runtime.h>
#include <hip/hip_bf16.h>
#include <stdint.h>

#define B_DIM 8192
#define D_DIM 2048
#define U_DIM 2048
#define DB    1024           // packed fp4 row stride in bytes (2048 elems / 2)
#define KWORDS 64            // bit path: 2048 bits = 64 u32 words

typedef int   v4i  __attribute__((ext_vector_type(4)));
typedef int   v8i  __attribute__((ext_vector_type(8)));
typedef float v16f __attribute__((ext_vector_type(16)));

// Async global->LDS DMA, 16B per lane. LDS dest is wave-uniform base + lane*16;
// global src may be per-lane arbitrary (we fold the bank swizzle there).
__device__ __forceinline__ void load_lds16(const char* g, char* l) {
    __builtin_amdgcn_global_load_lds(
        (const __attribute__((address_space(1))) unsigned int*)g,
        (__attribute__((address_space(3))) unsigned int*)l,
        16, 0, 0);
}

// Counted vmem wait: never drain to 0 in the main loop (T4).
#define WAITVM(n) asm volatile("s_waitcnt vmcnt(" #n ")" ::: "memory")
#define SBAR      __builtin_amdgcn_s_barrier()
#define SCHED0    __builtin_amdgcn_sched_barrier(0)
// rule #18: lgkmcnt(0) via inline asm must be followed by sched_barrier(0)
#define LGKM0     do { asm volatile("s_waitcnt lgkmcnt(0)" ::: "memory"); SCHED0; } while (0)

// ======================= MX-FP4 MFMA PATH =======================
// ste_sign values are exactly representable in fp4 e2m1: +1.0 = 0x2, -1.0 = 0xA.
// Products are +/-1, accumulated exactly in f32 (|sum| <= 2048 << 2^24).
// mfma_scale_f32_32x32x64_f8f6f4 with FMT=fp4 (cbsz=blgp=4) and unit E8M0
// scales (0x7F = 2^0) runs at ~9099 TOPS (2.07x the i8 ceiling) with K=64.

// R11 (proven): SINGLE pack dispatch. Blocks [0,1024) transpose-pack k (LDS
// path); blocks [1024, 1024+16384) pack x (pure streaming).
__global__ void pack_fp4(const float* __restrict__ x,
                         const float* __restrict__ k,
                         unsigned short* __restrict__ xq,
                         unsigned char* __restrict__ ktq) {
    __shared__ float tile[64][65];
    const int tid = threadIdx.x;

    if (blockIdx.x >= 1024) {
        // ---- x path: [B][D] f32 -> [B][D/2] fp4. float4 in, ushort out. ----
        int idx = (blockIdx.x - 1024) * 256 + tid;   // float4 index
        float4 v = ((const float4*)x)[idx];
        unsigned n0 = (v.x >= 0.f) ? 0x2u : 0xAu;
        unsigned n1 = (v.y >= 0.f) ? 0x2u : 0xAu;
        unsigned n2 = (v.z >= 0.f) ? 0x2u : 0xAu;
        unsigned n3 = (v.w >= 0.f) ? 0x2u : 0xAu;
        xq[idx] = (unsigned short)(n0 | (n1 << 4) | (n2 << 8) | (n3 << 12));
        return;
    }

    // ---- k path: [D][U] f32 -> [U][D/2] fp4 transposed via 64x64 LDS tile ----
    const int bid = blockIdx.x;
    const int j0 = (bid & 31) * 64;   // U tile
    const int d0 = (bid >> 5) * 64;   // D tile
    const int lane = tid & 63;
    const int wv = tid >> 6;
    for (int i = 0; i < 16; i++) {
        int row = i * 4 + wv;
        tile[row][lane] = k[(size_t)(d0 + row) * U_DIM + j0 + lane];
    }
    __syncthreads();
    const int u = tid >> 2;          // 0..63 output row (unit)
    const int q = tid & 3;           // 8-byte group along D (16 elems)
    unsigned long long ob = 0ull;
#pragma unroll
    for (int jj = 0; jj < 8; ++jj) {
        float lo = tile[q * 16 + 2 * jj][u];
        float hi = tile[q * 16 + 2 * jj + 1][u];
        unsigned byte = ((lo >= 0.f) ? 0x2u : 0xAu) | (((hi >= 0.f) ? 0x2u : 0xAu) << 4);
        ob |= (unsigned long long)byte << (8 * jj);
    }
    *(unsigned long long*)(ktq + (size_t)(j0 + u) * DB + (d0 >> 1) + q * 8) = ob;
}

// out[i][j] = sum_k sign(x)*sign(k) + bias[j], exact in f32 via fp4 MFMA.
//
// R12: fine-grained 8-phase interleave (the m201 template; m196 showed the
// COARSE phase-split - what R3/R10 did - is the inferior variant). Per K-tile
// 4 phases, each: {2-4 ds_read (frags for the NEXT phase) + 1 stage DMA,
// issued BEFORE the barrier so their DS service overlaps the barrier wait;
// SBAR; lgkm0; setprio(1); 4 MFMA; setprio(0); SBAR}. Counted WAITVM(7)
// once per tile at P2 (tiles t+2 and t+3-partial stay in flight - never 0
// until the tail 7->4->0). Frag flow (named sets, rule #20):
//   P0: MFMA a01*bA (kk0)  | read a23(kk0)          | stage A j0 (t+3)
//   P1: MFMA a23*bA (kk0)  | read a01,bB (kk1)      | stage A j1
//   P2: MFMA a01*bB (kk1)  | read a23(kk1) +vmcnt(7)| stage B j0
//   P3: MFMA a23*bB (kk1)  | read a01,bA (kk0,t+1)  | stage B j1
// Certification: vmcnt(7)+SBAR at P2 => tile t+1 landed CHIP-WIDE before
// P3's reads of buf[(t+1)&3]; stage into buf[(t-1)&3] at P0 is licensed by
// every wave's P2 lgkm-drain (last reads of that buf) + P3's barriers.
//
// Bank swizzle folded into the GLOBAL source (LDS dest stays linear for
// global_load_lds): within each 128B row-pair, 16B slot s <- s ^ (pair&7).
// Grid = 256 blocks = 1/CU; XCD swizzle: contiguous 32-block chunk per XCD.
__launch_bounds__(512, 2)
__global__ void gemm_fp4(const char* __restrict__ xq,   // [8192][1024]
                         const char* __restrict__ ktq,  // [2048][1024]
                         const float* __restrict__ bias,
                         float* __restrict__ out) {
    __shared__ uint4 lds[4][2048];   // [buf][ A:slots 0..1023 | B:1024..2047 ]

    const int tid  = threadIdx.x;
    const int lane = tid & 63;
    const int w    = tid >> 6;       // 8 waves
    const int m    = lane & 31;
    const int half = lane >> 5;

    // XCD-aware swizzle (nwg=256, 8 XCDs, 32 blocks/chunk; bijective)
    const int bid = blockIdx.x;
    const int swz = ((bid & 7) << 5) | (bid >> 3);
    const int bx  = swz & 7;         // U tile index [0,8)
    const int by  = swz >> 3;        // B tile index [0,32)
    const int rows0 = by << 8;
    const int cols0 = bx << 8;

    const int wr = (w >> 2) << 7;    // wave row offset: 0 or 128
    const int wc = (w & 3) << 6;     // wave col offset: 0/64/128/192

    v16f acc[4][2];
#pragma unroll
    for (int mi = 0; mi < 4; ++mi)
#pragma unroll
        for (int nj = 0; nj < 2; ++nj)
#pragma unroll
            for (int i = 0; i < 16; ++i) acc[mi][nj][i] = 0.0f;

    const char* abase = xq  + (size_t)rows0 * DB;
    const char* bbase = ktq + (size_t)cols0 * DB;

    // --- staging precompute: 2 A-slots + 2 B-slots per thread ---
    int   sbase[2];
    size_t goff0[2];
#pragma unroll
    for (int j = 0; j < 2; ++j) {
        sbase[j] = (w << 6) + (j << 9);          // wave-uniform LDS slot base
        const int s   = sbase[j] + lane;
        const int row = s >> 2, g = s & 3;
        const int p   = row >> 1;
        const int sl  = ((((row & 1) << 2) | g) ^ (p & 7));
        const int gr  = (p << 1) | (sl >> 2);
        const int gg  = sl & 3;
        goff0[j] = (size_t)gr * DB + (size_t)(gg << 4);
    }

    // --- fragment read offsets (loop-invariant; swizzled) ---
    int aoff[4][2], boff[2][2];
#pragma unroll
    for (int mi = 0; mi < 4; ++mi)
#pragma unroll
        for (int kk = 0; kk < 2; ++kk) {
            const int rl = wr + mi * 32 + m;
            const int gl = kk * 2 + half;
            const int p  = rl >> 1;
            const int st = ((((rl & 1) << 2) | gl) ^ (p & 7));
            aoff[mi][kk] = (p << 7) + (st << 4);
        }
#pragma unroll
    for (int nj = 0; nj < 2; ++nj)
#pragma unroll
        for (int kk = 0; kk < 2; ++kk) {
            const int rl = wc + nj * 32 + m;
            const int gl = kk * 2 + half;
            const int p  = rl >> 1;
            const int st = ((((rl & 1) << 2) | gl) ^ (p & 7));
            boff[nj][kk] = 16384 + (p << 7) + (st << 4);
        }

    // fp4 operands occupy the LOW 4 regs of the v8i MFMA operand;
    // high halves zeroed ONCE (named sets, rule #20).
    typedef union { v8i v8; v4i v4[2]; } opnd_t;
    opnd_t a01_0, a01_1, a23_0, a23_1, bA0, bA1, bB0, bB1;
    a01_0.v4[1] = (v4i){0,0,0,0}; a01_1.v4[1] = (v4i){0,0,0,0};
    a23_0.v4[1] = (v4i){0,0,0,0}; a23_1.v4[1] = (v4i){0,0,0,0};
    bA0.v4[1]   = (v4i){0,0,0,0}; bA1.v4[1]   = (v4i){0,0,0,0};
    bB0.v4[1]   = (v4i){0,0,0,0}; bB1.v4[1]   = (v4i){0,0,0,0};

#define RD_A01(buf, kk) do { const char* Ls_ = (const char*)lds[buf];      \
        a01_0.v4[0] = *(const v4i*)(Ls_ + aoff[0][kk]);                    \
        a01_1.v4[0] = *(const v4i*)(Ls_ + aoff[1][kk]); } while (0)
#define RD_A23(buf, kk) do { const char* Ls_ = (const char*)lds[buf];      \
        a23_0.v4[0] = *(const v4i*)(Ls_ + aoff[2][kk]);                    \
        a23_1.v4[0] = *(const v4i*)(Ls_ + aoff[3][kk]); } while (0)
#define RD_BA(buf, kk) do { const char* Ls_ = (const char*)lds[buf];       \
        bA0.v4[0] = *(const v4i*)(Ls_ + boff[0][kk]);                      \
        bA1.v4[0] = *(const v4i*)(Ls_ + boff[1][kk]); } while (0)
#define RD_BB(buf, kk) do { const char* Ls_ = (const char*)lds[buf];       \
        bB0.v4[0] = *(const v4i*)(Ls_ + boff[0][kk]);                      \
        bB1.v4[0] = *(const v4i*)(Ls_ + boff[1][kk]); } while (0)
#define MFMA1(A, Bv, r, c) acc[r][c] =                                     \
        __builtin_amdgcn_mfma_scale_f32_32x32x64_f8f6f4(                   \
            A.v8, Bv.v8, acc[r][c], 4, 4, 0, 0x7F7F7F7Fu, 0, 0x7F7F7F7Fu)
#define MMA4(A0, A1, B0v, B1v, r0, r1) do {                                \
        __builtin_amdgcn_s_setprio(1);                                     \
        MFMA1(A0, B0v, r0, 0); MFMA1(A0, B1v, r0, 1);                      \
        MFMA1(A1, B0v, r1, 0); MFMA1(A1, B1v, r1, 1);                      \
        __builtin_amdgcn_s_setprio(0); } while (0)

    auto stageA1 = [&](int t, int buf, int j) {
        load_lds16(abase + goff0[j] + ((size_t)t << 6), (char*)&lds[buf][sbase[j]]);
    };
    auto stageB1 = [&](int t, int buf, int j) {
        load_lds16(bbase + goff0[j] + ((size_t)t << 6), (char*)&lds[buf][1024 + sbase[j]]);
    };

    // prologue: fully stage tiles 0,1,2 (12 loads/thread: A0,A1,B0,B1 each)
#pragma unroll
    for (int tt = 0; tt < 3; ++tt) {
        stageA1(tt, tt, 0); stageA1(tt, tt, 1);
        stageB1(tt, tt, 0); stageB1(tt, tt, 1);
    }
    WAITVM(8);                        // tile 0 landed (own; tiles 1,2 = 8 out)
    SBAR;                             // ... chip-wide
    RD_A01(0, 0); RD_BA(0, 0);        // frags for tile 0 phase P0

    // main loop: tiles 0..12; stage tile t+3 one load per phase
#pragma unroll 1
    for (int t = 0; t < 13; ++t) {
        const int cb = t & 3, nb = (t + 3) & 3, nx = (t + 1) & 3;
        // P0: MFMA a01*bA(kk0) | read a23(kk0) | stage A0
        RD_A23(cb, 0);  stageA1(t + 3, nb, 0);
        SBAR; LGKM0; MMA4(a01_0, a01_1, bA0, bA1, 0, 1); SBAR;
        // P1: MFMA a23*bA(kk0) | read a01,bB(kk1) | stage A1
        RD_A01(cb, 1);  RD_BB(cb, 1);  stageA1(t + 3, nb, 1);
        SBAR; LGKM0; MMA4(a23_0, a23_1, bA0, bA1, 2, 3); SBAR;
        // P2: MFMA a01*bB(kk1) | read a23(kk1) | stage B0 | vmcnt(7): t+1 landed
        RD_A23(cb, 1);  stageB1(t + 3, nb, 0);
        WAITVM(7);
        SBAR; LGKM0; MMA4(a01_0, a01_1, bB0, bB1, 0, 1); SBAR;
        // P3: MFMA a23*bB(kk1) | read next tile a01,bA(kk0) | stage B1
        RD_A01(nx, 0);  RD_BA(nx, 0);  stageB1(t + 3, nb, 1);
        SBAR; LGKM0; MMA4(a23_0, a23_1, bB0, bB1, 2, 3); SBAR;
    }
    // peeled t=13 (buf 1): no staging; vmcnt 4 (tile 15's loads stay out)
    {
        RD_A23(1, 0);
        SBAR; LGKM0; MMA4(a01_0, a01_1, bA0, bA1, 0, 1); SBAR;
        RD_A01(1, 1);  RD_BB(1, 1);
        SBAR; LGKM0; MMA4(a23_0, a23_1, bA0, bA1, 2, 3); SBAR;
        RD_A23(1, 1);
        WAITVM(4);
        SBAR; LGKM0; MMA4(a01_0, a01_1, bB0, bB1, 0, 1); SBAR;
        RD_A01(2, 0);  RD_BA(2, 0);
        SBAR; LGKM0; MMA4(a23_0, a23_1, bB0, bB1, 2, 3); SBAR;
    }
    // peeled t=14 (buf 2): drain to 0 at P2 (tile 15 landed)
    {
        RD_A23(2, 0);
        SBAR; LGKM0; MMA4(a01_0, a01_1, bA0, bA1, 0, 1); SBAR;
        RD_A01(2, 1);  RD_BB(2, 1);
        SBAR; LGKM0; MMA4(a23_0, a23_1, bA0, bA1, 2, 3); SBAR;
        RD_A23(2, 1);
        WAITVM(0);
        SBAR; LGKM0; MMA4(a01_0, a01_1, bB0, bB1, 0, 1); SBAR;
        RD_A01(3, 0);  RD_BA(3, 0);
        SBAR; LGKM0; MMA4(a23_0, a23_1, bB0, bB1, 2, 3); SBAR;
    }
    // peeled t=15 (buf 3): everything resident
    {
        RD_A23(3, 0);
        SBAR; LGKM0; MMA4(a01_0, a01_1, bA0, bA1, 0, 1); SBAR;
        RD_A01(3, 1);  RD_BB(3, 1);
        SBAR; LGKM0; MMA4(a23_0, a23_1, bA0, bA1, 2, 3); SBAR;
        RD_A23(3, 1);
        SBAR; LGKM0; MMA4(a01_0, a01_1, bB0, bB1, 0, 1); SBAR;
        LGKM0; MMA4(a23_0, a23_1, bB0, bB1, 2, 3);
    }
#undef RD_A01
#undef RD_A23
#undef RD_BA
#undef RD_BB
#undef MFMA1
#undef MMA4

    // C/D 32x32 layout (HW-verified, shape-determined not dtype-determined):
    // col = lane&31, row = (reg&3)+8*(reg>>2)+4*half. acc is already f32.
#pragma unroll
    for (int mi = 0; mi < 4; ++mi)
#pragma unroll
        for (int nj = 0; nj < 2; ++nj) {
            const int n = cols0 + wc + nj * 32 + m;
            const float bb = bias[n];
#pragma unroll
            for (int reg = 0; reg < 16; ++reg) {
                const int row = (reg & 3) + 8 * (reg >> 2) + 4 * half;
                const size_t grow = (size_t)(rows0 + wr + mi * 32 + row);
                out[grow * U_DIM + n] = acc[mi][nj][reg] + bb;
            }
        }
}

// ======================= BIT-PATH FALLBACK (R5, proven) =======================

__global__ void pack_x_kernel(const float* __restrict__ x,
                              unsigned long long* __restrict__ xb) {
    const int gwave = (blockIdx.x * blockDim.x + threadIdx.x) >> 6;
    const int lane  = threadIdx.x & 63;
    const size_t base = (size_t)gwave * 256;
    float v0 = x[base + lane];
    float v1 = x[base + 64 + lane];
    float v2 = x[base + 128 + lane];
    float v3 = x[base + 192 + lane];
    unsigned long long m0 = __ballot(v0 >= 0.0f);
    unsigned long long m1 = __ballot(v1 >= 0.0f);
    unsigned long long m2 = __ballot(v2 >= 0.0f);
    unsigned long long m3 = __ballot(v3 >= 0.0f);
    if (lane == 0) {
        ulonglong2* p = (ulonglong2*)(xb + (base >> 6));
        ulonglong2 a; a.x = m0; a.y = m1;
        ulonglong2 b; b.x = m2; b.y = m3;
        p[0] = a;
        p[1] = b;
    }
}

__global__ void pack_k_kernel(const float* __restrict__ k,
                              unsigned long long* __restrict__ kb) {
    __shared__ float tile[64][65];
    const int j0 = (blockIdx.x & 31) * 64;
    const int d0 = (blockIdx.x >> 5) * 64;
    const int tid  = threadIdx.x;
    const int lane = tid & 63;
    const int wv   = tid >> 6;
    for (int i = 0; i < 16; i++) {
        int row = i * 4 + wv;
        tile[row][lane] = k[(size_t)(d0 + row) * U_DIM + j0 + lane];
    }
    __syncthreads();
    for (int c = wv * 16; c < wv * 16 + 16; c++) {
        float v = tile[lane][c];
        unsigned long long m = __ballot(v >= 0.0f);
        if (lane == 0) kb[(size_t)(j0 + c) * (D_DIM / 64) + (d0 >> 6)] = m;
    }
}

__launch_bounds__(512)
__global__ void bgemm_kernel(const unsigned int* __restrict__ xb,
                             const unsigned int* __restrict__ kb,
                             const float* __restrict__ bias,
                             float* __restrict__ out) {
    __shared__ unsigned int xs[128 * KWORDS];
    __shared__ unsigned int ks[128 * KWORDS];
    const int bx  = blockIdx.x;
    const int by  = blockIdx.y;
    const int tid = threadIdx.x;
    const uint4* xsrc = (const uint4*)(xb + (size_t)(by * 128) * KWORDS);
    const uint4* ksrc = (const uint4*)(kb + (size_t)(bx * 128) * KWORDS);
#pragma unroll
    for (int i = 0; i < 4; i++) {
        int flat = tid + i * 512;
        int r    = flat >> 4;
        int g    = flat & 15;
        int sg   = g ^ ((r >> 3) & 7);
        uint4 xv = xsrc[flat];
        uint4 kv = ksrc[flat];
        *((uint4*)&xs[r * KWORDS + sg * 4]) = xv;
        *((uint4*)&ks[r * KWORDS + sg * 4]) = kv;
    }
    __syncthreads();
    const int tr   = (tid >> 4) * 4;
    const int tc   = (tid & 15) * 8;
    const int xswz = ((tid >> 4) >> 1) & 7;
    const int ksw  = tid & 7;
    int acc[4][8] = {};
    for (int w4 = 0; w4 < 16; w4++) {
        const int xcol = (w4 ^ xswz) * 4;
        const int kcol = (w4 ^ ksw) * 4;
        uint4 xv[4], kv[8];
#pragma unroll
        for (int r = 0; r < 4; r++) xv[r] = *((const uint4*)&xs[(tr + r) * KWORDS + xcol]);
#pragma unroll
        for (int c = 0; c < 8; c++) kv[c] = *((const uint4*)&ks[(tc + c) * KWORDS + kcol]);
#pragma unroll
        for (int r = 0; r < 4; r++)
#pragma unroll
            for (int c = 0; c < 8; c++) {
                acc[r][c] += __popc(xv[r].x ^ kv[c].x);
                acc[r][c] += __popc(xv[r].y ^ kv[c].y);
                acc[r][c] += __popc(xv[r].z ^ kv[c].z);
                acc[r][c] += __popc(xv[r].w ^ kv[c].w);
            }
    }
    const int row0 = by * 128 + tr;
    const int col0 = bx * 128 + tc;
    const float4 b0 = *((const float4*)&bias[col0]);
    const float4 b1 = *((const float4*)&bias[col0 + 4]);
#pragma unroll
    for (int r = 0; r < 4; r++) {
        float4 o0, o1;
        o0.x = (float)(D_DIM - 2 * acc[r][0]) + b0.x;
        o0.y = (float)(D_DIM - 2 * acc[r][1]) + b0.y;
        o0.z = (float)(D_DIM - 2 * acc[r][2]) + b0.z;
        o0.w = (float)(D_DIM - 2 * acc[r][3]) + b0.w;
        o1.x = (float)(D_DIM - 2 * acc[r][4]) + b1.x;
        o1.y = (float)(D_DIM - 2 * acc[r][5]) + b1.y;
        o1.z = (float)(D_DIM - 2 * acc[r][6]) + b1.z;
        o1.w = (float)(D_DIM - 2 * acc[r][7]) + b1.w;
        float* orow = &out[(size_t)(row0 + r) * U_DIM + col0];
        *((float4*)orow)       = o0;
        *((float4*)(orow + 4)) = o1;
    }
}

// ======================= launcher =======================

extern "C" void kernel_launch(void* const* d_in, const int* in_sizes, int n_in,
                              void* d_out, int out_size, void* d_ws, size_t ws_size,
                              hipStream_t stream) {
    const float* x    = (const float*)d_in[0];   // [8192][2048]
    const float* k    = (const float*)d_in[1];   // [2048][2048]
    const float* bias = (const float*)d_in[2];   // [2048]
    float* out = (float*)d_out;

    const size_t need_fp4 = (size_t)B_DIM * DB + (size_t)U_DIM * DB; // ~10 MB
    if (ws_size >= need_fp4) {
        unsigned short* xq = (unsigned short*)d_ws;                  // 8 MB
        unsigned char*  ktq = (unsigned char*)d_ws + (size_t)B_DIM * DB; // 2 MB
        // single pack dispatch: 1024 kt-blocks + 16384 x-blocks
        pack_fp4<<<1024 + (B_DIM * D_DIM) / 1024, 256, 0, stream>>>(x, k, xq, ktq);
        gemm_fp4<<<256, 512, 0, stream>>>((const char*)xq, (const char*)ktq, bias, out);
    } else {
        unsigned long long* xbits = (unsigned long long*)d_ws;
        unsigned long long* kbits = (unsigned long long*)((char*)d_ws + (size_t)B_DIM * (D_DIM / 8));
        pack_x_kernel<<<(B_DIM * D_DIM) / 1024, 256, 0, stream>>>(x, xbits);
        pack_k_kernel<<<32 * 32, 256, 0, stream>>>(k, kbits);
        dim3 grid(U_DIM / 128, B_DIM / 128);
        bgemm_kernel<<<grid, 512, 0, stream>>>((const unsigned int*)xbits,
                                               (const unsigned int*)kbits, bias, out);
    }
}